// Round 2
// baseline (550.110 us; speedup 1.0000x reference)
//
#include <hip/hip_runtime.h>

#define WDIM 192
#define PLANE (192 * 192)
#define VOL (192 * 192 * 192)

__global__ void zero_out_k(float* out) { out[0] = 0.0f; }

// --- Pass 1: fused W-box + H-box sum of the 5 derived fields ---------------
// Thread = (w, d) column, slides along H with a 9-deep register ring.
// blockIdx.x = d*4 + h_chunk  (per batch launch). 192 threads = W line.
// Per step: 9-tap W-window recomputed from guarded scalar loads (L1 lines
// are shared across the wave's consecutive lanes).
__global__ __launch_bounds__(192) void wh_pass(const float* __restrict__ I,
                                               const float* __restrict__ J,
                                               float* __restrict__ B) {
    const int t = threadIdx.x;          // w
    const int d = blockIdx.x >> 2;
    const int c = blockIdx.x & 3;
    const int h0 = c * 48;

    const float* Ib = I + (size_t)d * PLANE;
    const float* Jb = J + (size_t)d * PLANE;

    float ring0[9], ring1[9], ring2[9], ring3[9], ring4[9];
    #pragma unroll
    for (int j = 0; j < 9; ++j) { ring0[j]=0.f; ring1[j]=0.f; ring2[j]=0.f; ring3[j]=0.f; ring4[j]=0.f; }
    float s0 = 0.f, s1 = 0.f, s2 = 0.f, s3 = 0.f, s4 = 0.f;

    // steps s = 0..55 : h_in = h0-4+s ; emit h_out = h_in-4 for s in [8,55]
    for (int o = 0; o < 7; ++o) {
        #pragma unroll
        for (int j = 0; j < 9; ++j) {
            const int s = o * 9 + j;
            if (s <= 55) {
                const int h_in = h0 - 4 + s;
                float w0 = 0.f, w1 = 0.f, w2 = 0.f, w3 = 0.f, w4 = 0.f;
                if (h_in >= 0 && h_in < WDIM) {
                    const float* rowI = Ib + h_in * WDIM;
                    const float* rowJ = Jb + h_in * WDIM;
                    #pragma unroll
                    for (int k = 0; k < 9; ++k) {
                        const int w = t - 4 + k;
                        if (w >= 0 && w < WDIM) {
                            float vi = rowI[w];
                            float vj = rowJ[w];
                            w0 += vi; w1 += vj;
                            w2 += vi * vi; w3 += vj * vj; w4 += vi * vj;
                        }
                    }
                }
                // slide: add new, drop 9-old (static ring index j)
                s0 += w0 - ring0[j]; ring0[j] = w0;
                s1 += w1 - ring1[j]; ring1[j] = w1;
                s2 += w2 - ring2[j]; ring2[j] = w2;
                s3 += w3 - ring3[j]; ring3[j] = w3;
                s4 += w4 - ring4[j]; ring4[j] = w4;

                if (s >= 8) {
                    const int h_out = h_in - 4;   // in [h0, h0+48)
                    const size_t idx = (size_t)d * PLANE + h_out * WDIM + t;
                    B[0 * (size_t)VOL + idx] = s0;
                    B[1 * (size_t)VOL + idx] = s1;
                    B[2 * (size_t)VOL + idx] = s2;
                    B[3 * (size_t)VOL + idx] = s3;
                    B[4 * (size_t)VOL + idx] = s4;
                }
            }
        }
    }
}

// --- Pass 2: D-axis sliding box sum + NCC formula + reduction -------------
// blockIdx.x = h*4 + d_chunk (per batch launch); 192 threads cover W.
__global__ __launch_bounds__(192) void d_pass(const float* __restrict__ B,
                                              const float* __restrict__ I,
                                              const float* __restrict__ J,
                                              float* __restrict__ out) {
    const int t = threadIdx.x;
    const int h = blockIdx.x >> 2;
    const int c = blockIdx.x & 3;
    const int d0 = c * 48;
    const int base_h = h * WDIM + t;

    float s0 = 0.f, s1 = 0.f, s2 = 0.f, s3 = 0.f, s4 = 0.f;
    for (int d = d0 - 4; d <= d0 + 3; ++d) {
        if (d >= 0) {
            const size_t idx = (size_t)d * PLANE + base_h;
            s0 += B[0 * (size_t)VOL + idx];
            s1 += B[1 * (size_t)VOL + idx];
            s2 += B[2 * (size_t)VOL + idx];
            s3 += B[3 * (size_t)VOL + idx];
            s4 += B[4 * (size_t)VOL + idx];
        }
    }

    const float inv_k = 1.0f / 729.0f;
    float local = 0.f;
    for (int dd = d0; dd < d0 + 48; ++dd) {
        const int da = dd + 4;
        if (da <= WDIM - 1) {
            const size_t idx = (size_t)da * PLANE + base_h;
            s0 += B[0 * (size_t)VOL + idx];
            s1 += B[1 * (size_t)VOL + idx];
            s2 += B[2 * (size_t)VOL + idx];
            s3 += B[3 * (size_t)VOL + idx];
            s4 += B[4 * (size_t)VOL + idx];
        }
        const size_t idx = (size_t)dd * PLANE + base_h;
        float vi = I[idx];
        float vj = J[idx];
        float Iu = vi * inv_k;
        float Ju = vj * inv_k;
        float cross = s4 - s0 * Ju - s1 * Iu + Iu * Ju * 729.0f;
        float Ivar  = s2 - 2.0f * s0 * Iu + Iu * Iu * 729.0f;
        float Jvar  = s3 - 2.0f * s1 * Ju + Ju * Ju * 729.0f;
        local += (cross * cross) / (Ivar * Jvar + 1e-5f);
        const int ds = dd - 4;
        if (ds >= 0) {
            const size_t idx2 = (size_t)ds * PLANE + base_h;
            s0 -= B[0 * (size_t)VOL + idx2];
            s1 -= B[1 * (size_t)VOL + idx2];
            s2 -= B[2 * (size_t)VOL + idx2];
            s3 -= B[3 * (size_t)VOL + idx2];
            s4 -= B[4 * (size_t)VOL + idx2];
        }
    }

    __shared__ float sred[192];
    sred[t] = local;
    __syncthreads();
    if (t < 64) {
        float v = sred[t] + sred[t + 64] + sred[t + 128];
        #pragma unroll
        for (int off = 32; off; off >>= 1) v += __shfl_down(v, off);
        if (t == 0) {
            atomicAdd(out, v * (-1.0f / 14155776.0f));
        }
    }
}

extern "C" void kernel_launch(void* const* d_in, const int* in_sizes, int n_in,
                              void* d_out, int out_size, void* d_ws, size_t ws_size,
                              hipStream_t stream) {
    const float* I = (const float*)d_in[0];
    const float* J = (const float*)d_in[1];
    float* out = (float*)d_out;

    // Workspace: one 5-field HW-summed volume, reused per batch: 141.6 MB.
    float* B = (float*)d_ws;

    zero_out_k<<<1, 1, 0, stream>>>(out);

    for (int b = 0; b < 2; ++b) {
        const float* Ib = I + (size_t)b * VOL;
        const float* Jb = J + (size_t)b * VOL;
        wh_pass<<<192 * 4, 192, 0, stream>>>(Ib, Jb, B);
        d_pass<<<192 * 4, 192, 0, stream>>>(B, Ib, Jb, out);
    }
}

// Round 3
// 333.208 us; speedup vs baseline: 1.6509x; 1.6509x over previous
//
#include <hip/hip_runtime.h>

#define WDIM 192
#define PLANE (192 * 192)
#define VOL (192 * 192 * 192)
#define HC 24          // h-rows produced per block in wh_pass
#define TR (HC + 8)    // tile rows incl. halo = 32

__global__ void zero_out_k(float* out) { out[0] = 0.0f; }

// --- Pass 1: fused W-box + H-box sums of the 5 derived fields --------------
// Block: d fixed, h-chunk of HC=24, 192 threads = W line.
// Stage 32x192 tile of I and J in LDS (48 KB) via float4, then each thread
// slides along H with a 9-deep register ring of W-window sums.
__global__ __launch_bounds__(192) void wh_pass(const float* __restrict__ I,
                                               const float* __restrict__ J,
                                               float* __restrict__ B) {
    __shared__ float sI[TR * WDIM];
    __shared__ float sJ[TR * WDIM];
    const int t = threadIdx.x;           // w
    const int d = blockIdx.x >> 3;
    const int c = blockIdx.x & 7;
    const int h0 = c * HC;

    const size_t dbase = (size_t)d * PLANE;

    // Cooperative tile load: TR*WDIM = 6144 floats per field = 1536 float4.
    // 8 float4 per thread per field; rows outside [0,192) stage as zeros.
    #pragma unroll
    for (int i = 0; i < 8; ++i) {
        const int idx4 = i * 192 + t;        // 0..1535
        const int row  = idx4 / 48;          // tile row 0..31
        const int col4 = (idx4 - row * 48) * 4;
        const int h = h0 - 4 + row;
        float4 vI = make_float4(0.f, 0.f, 0.f, 0.f);
        float4 vJ = vI;
        if (h >= 0 && h < WDIM) {
            vI = *(const float4*)(I + dbase + (size_t)h * WDIM + col4);
            vJ = *(const float4*)(J + dbase + (size_t)h * WDIM + col4);
        }
        *(float4*)&sI[row * WDIM + col4] = vI;
        *(float4*)&sJ[row * WDIM + col4] = vJ;
    }
    __syncthreads();

    float ring0[9], ring1[9], ring2[9], ring3[9], ring4[9];
    #pragma unroll
    for (int j = 0; j < 9; ++j) { ring0[j]=0.f; ring1[j]=0.f; ring2[j]=0.f; ring3[j]=0.f; ring4[j]=0.f; }
    float s0 = 0.f, s1 = 0.f, s2 = 0.f, s3 = 0.f, s4 = 0.f;

    // steps s = 0..31 over tile rows; emit h_out = h0 + s - 8 for s >= 8
    #pragma unroll
    for (int o = 0; o < 4; ++o) {
        #pragma unroll
        for (int j = 0; j < 9; ++j) {
            const int s = o * 9 + j;
            if (s < TR) {
                float w0 = 0.f, w1 = 0.f, w2 = 0.f, w3 = 0.f, w4 = 0.f;
                #pragma unroll
                for (int k = 0; k < 9; ++k) {
                    const int w = t - 4 + k;
                    if (w >= 0 && w < WDIM) {
                        float a = sI[s * WDIM + w];
                        float b = sJ[s * WDIM + w];
                        w0 += a; w1 += b;
                        w2 += a * a; w3 += b * b; w4 += a * b;
                    }
                }
                s0 += w0 - ring0[j]; ring0[j] = w0;
                s1 += w1 - ring1[j]; ring1[j] = w1;
                s2 += w2 - ring2[j]; ring2[j] = w2;
                s3 += w3 - ring3[j]; ring3[j] = w3;
                s4 += w4 - ring4[j]; ring4[j] = w4;

                if (s >= 8) {
                    const int h_out = h0 + s - 8;
                    const size_t idx = dbase + (size_t)h_out * WDIM + t;
                    B[0 * (size_t)VOL + idx] = s0;
                    B[1 * (size_t)VOL + idx] = s1;
                    B[2 * (size_t)VOL + idx] = s2;
                    B[3 * (size_t)VOL + idx] = s3;
                    B[4 * (size_t)VOL + idx] = s4;
                }
            }
        }
    }
}

// --- Pass 2: D-axis sliding box sum + NCC formula + reduction --------------
// Block: h fixed, d-chunk of 24, 192 threads cover W. 1536 blocks/batch.
__global__ __launch_bounds__(192) void d_pass(const float* __restrict__ B,
                                              const float* __restrict__ I,
                                              const float* __restrict__ J,
                                              float* __restrict__ out) {
    const int t = threadIdx.x;
    const int h = blockIdx.x >> 3;
    const int c = blockIdx.x & 7;
    const int d0 = c * 24;
    const int base_h = h * WDIM + t;

    float s0 = 0.f, s1 = 0.f, s2 = 0.f, s3 = 0.f, s4 = 0.f;
    #pragma unroll
    for (int dw = -4; dw <= 3; ++dw) {
        const int d = d0 + dw;
        if (d >= 0) {
            const size_t idx = (size_t)d * PLANE + base_h;
            s0 += B[0 * (size_t)VOL + idx];
            s1 += B[1 * (size_t)VOL + idx];
            s2 += B[2 * (size_t)VOL + idx];
            s3 += B[3 * (size_t)VOL + idx];
            s4 += B[4 * (size_t)VOL + idx];
        }
    }

    const float inv_k = 1.0f / 729.0f;
    float local = 0.f;
    for (int dd = d0; dd < d0 + 24; ++dd) {
        const int da = dd + 4;
        if (da <= WDIM - 1) {
            const size_t idx = (size_t)da * PLANE + base_h;
            s0 += B[0 * (size_t)VOL + idx];
            s1 += B[1 * (size_t)VOL + idx];
            s2 += B[2 * (size_t)VOL + idx];
            s3 += B[3 * (size_t)VOL + idx];
            s4 += B[4 * (size_t)VOL + idx];
        }
        const size_t idx = (size_t)dd * PLANE + base_h;
        float vi = I[idx];
        float vj = J[idx];
        float Iu = vi * inv_k;
        float Ju = vj * inv_k;
        float cross = s4 - s0 * Ju - s1 * Iu + Iu * Ju * 729.0f;
        float Ivar  = s2 - 2.0f * s0 * Iu + Iu * Iu * 729.0f;
        float Jvar  = s3 - 2.0f * s1 * Ju + Ju * Ju * 729.0f;
        local += (cross * cross) / (Ivar * Jvar + 1e-5f);
        const int ds = dd - 4;
        if (ds >= 0) {
            const size_t idx2 = (size_t)ds * PLANE + base_h;
            s0 -= B[0 * (size_t)VOL + idx2];
            s1 -= B[1 * (size_t)VOL + idx2];
            s2 -= B[2 * (size_t)VOL + idx2];
            s3 -= B[3 * (size_t)VOL + idx2];
            s4 -= B[4 * (size_t)VOL + idx2];
        }
    }

    __shared__ float sred[192];
    sred[t] = local;
    __syncthreads();
    if (t < 64) {
        float v = sred[t] + sred[t + 64] + sred[t + 128];
        #pragma unroll
        for (int off = 32; off; off >>= 1) v += __shfl_down(v, off);
        if (t == 0) {
            atomicAdd(out, v * (-1.0f / 14155776.0f));
        }
    }
}

extern "C" void kernel_launch(void* const* d_in, const int* in_sizes, int n_in,
                              void* d_out, int out_size, void* d_ws, size_t ws_size,
                              hipStream_t stream) {
    const float* I = (const float*)d_in[0];
    const float* J = (const float*)d_in[1];
    float* out = (float*)d_out;

    // Workspace: one 5-field HW-summed volume, reused per batch: 141.6 MB.
    float* B = (float*)d_ws;

    zero_out_k<<<1, 1, 0, stream>>>(out);

    for (int b = 0; b < 2; ++b) {
        const float* Ib = I + (size_t)b * VOL;
        const float* Jb = J + (size_t)b * VOL;
        wh_pass<<<192 * 8, 192, 0, stream>>>(Ib, Jb, B);
        d_pass<<<192 * 8, 192, 0, stream>>>(B, Ib, Jb, out);
    }
}

// Round 4
// 274.875 us; speedup vs baseline: 2.0013x; 1.2122x over previous
//
#include <hip/hip_runtime.h>
#include <hip/hip_bf16.h>

#define WDIM 192
#define PLANE (192 * 192)
#define VOL (192 * 192 * 192)
#define HC 24          // h-rows produced per block in wh_pass
#define TR (HC + 8)    // tile rows incl. halo = 32
#define DC 24          // d-slices per block in d_pass

__global__ void zero_out_k(float* out) { out[0] = 0.0f; }

// pack two floats -> one uint holding 2 bf16 (RN), lo = a, hi = b
static __device__ inline unsigned int pk_bf16(float a, float b) {
    union { __hip_bfloat162 v; unsigned int u; } cvt;
    cvt.v = __float22bfloat162_rn(make_float2(a, b));
    return cvt.u;
}
static __device__ inline float bf_lo(unsigned int u) {
    union { unsigned int u; float f; } c; c.u = u << 16; return c.f;
}
static __device__ inline float bf_hi(unsigned int u) {
    union { unsigned int u; float f; } c; c.u = u & 0xffff0000u; return c.f;
}

// --- Pass 1: fused W-box + H-box sums -> packed bf16x8 per voxel -----------
// fields: x=(Isum,Jsum) y=(IIsum,JJsum) z=(IJsum,cI) w=(cJ,0)
__global__ __launch_bounds__(192) void wh_pass(const float* __restrict__ I,
                                               const float* __restrict__ J,
                                               uint4* __restrict__ B) {
    __shared__ float sI[TR * WDIM];
    __shared__ float sJ[TR * WDIM];
    const int t = threadIdx.x;           // w
    const int d = blockIdx.x >> 3;
    const int c = blockIdx.x & 7;
    const int h0 = c * HC;

    const size_t dbase = (size_t)d * PLANE;

    #pragma unroll
    for (int i = 0; i < 8; ++i) {
        const int idx4 = i * 192 + t;        // 0..1535
        const int row  = idx4 / 48;          // tile row 0..31
        const int col4 = (idx4 - row * 48) * 4;
        const int h = h0 - 4 + row;
        float4 vI = make_float4(0.f, 0.f, 0.f, 0.f);
        float4 vJ = vI;
        if (h >= 0 && h < WDIM) {
            vI = *(const float4*)(I + dbase + (size_t)h * WDIM + col4);
            vJ = *(const float4*)(J + dbase + (size_t)h * WDIM + col4);
        }
        *(float4*)&sI[row * WDIM + col4] = vI;
        *(float4*)&sJ[row * WDIM + col4] = vJ;
    }
    __syncthreads();

    float ring0[9], ring1[9], ring2[9], ring3[9], ring4[9];
    #pragma unroll
    for (int j = 0; j < 9; ++j) { ring0[j]=0.f; ring1[j]=0.f; ring2[j]=0.f; ring3[j]=0.f; ring4[j]=0.f; }
    float s0 = 0.f, s1 = 0.f, s2 = 0.f, s3 = 0.f, s4 = 0.f;

    #pragma unroll
    for (int o = 0; o < 4; ++o) {
        #pragma unroll
        for (int j = 0; j < 9; ++j) {
            const int s = o * 9 + j;
            if (s < TR) {
                float w0 = 0.f, w1 = 0.f, w2 = 0.f, w3 = 0.f, w4 = 0.f;
                #pragma unroll
                for (int k = 0; k < 9; ++k) {
                    const int w = t - 4 + k;
                    if (w >= 0 && w < WDIM) {
                        float a = sI[s * WDIM + w];
                        float b = sJ[s * WDIM + w];
                        w0 += a; w1 += b;
                        w2 += a * a; w3 += b * b; w4 += a * b;
                    }
                }
                s0 += w0 - ring0[j]; ring0[j] = w0;
                s1 += w1 - ring1[j]; ring1[j] = w1;
                s2 += w2 - ring2[j]; ring2[j] = w2;
                s3 += w3 - ring3[j]; ring3[j] = w3;
                s4 += w4 - ring4[j]; ring4[j] = w4;

                if (s >= 8) {
                    const int h_out = h0 + s - 8;
                    // center I,J for this output voxel (staged row s-4)
                    const float ci = sI[(s - 4) * WDIM + t];
                    const float cj = sJ[(s - 4) * WDIM + t];
                    uint4 q;
                    q.x = pk_bf16(s0, s1);
                    q.y = pk_bf16(s2, s3);
                    q.z = pk_bf16(s4, ci);
                    q.w = pk_bf16(cj, 0.f);
                    B[dbase + (size_t)h_out * WDIM + t] = q;
                }
            }
        }
    }
}

// --- Pass 2: D-axis sliding box sum + NCC + reduction ----------------------
// One uint4 load per step; subtract-slice & center values come from a
// 9-deep register ring (statically indexed via 9x unrolled loop).
__global__ __launch_bounds__(192) void d_pass(const uint4* __restrict__ B,
                                              float* __restrict__ out) {
    const int t = threadIdx.x;
    const int h = blockIdx.x >> 3;
    const int c = blockIdx.x & 7;
    const int d0 = c * DC;
    const int base_h = h * WDIM + t;

    float r0[9], r1[9], r2[9], r3[9], r4[9], rI[9], rJ[9];
    #pragma unroll
    for (int j = 0; j < 9; ++j) { r0[j]=0.f; r1[j]=0.f; r2[j]=0.f; r3[j]=0.f; r4[j]=0.f; rI[j]=0.f; rJ[j]=0.f; }
    float s0 = 0.f, s1 = 0.f, s2 = 0.f, s3 = 0.f, s4 = 0.f;

    const float inv_k = 1.0f / 729.0f;
    float local = 0.f;

    // steps s = 0..DC+7 : d_in = d0-4+s ; emit d_out = d_in-4 for s >= 8
    #pragma unroll
    for (int o = 0; o < 4; ++o) {
        #pragma unroll
        for (int j = 0; j < 9; ++j) {
            const int s = o * 9 + j;
            if (s < DC + 8) {
                const int d_in = d0 - 4 + s;
                float f0=0.f, f1=0.f, f2=0.f, f3=0.f, f4=0.f, f5=0.f, f6=0.f;
                if (d_in >= 0 && d_in < WDIM) {
                    const uint4 q = B[(size_t)d_in * PLANE + base_h];
                    f0 = bf_lo(q.x); f1 = bf_hi(q.x);
                    f2 = bf_lo(q.y); f3 = bf_hi(q.y);
                    f4 = bf_lo(q.z); f5 = bf_hi(q.z);
                    f6 = bf_lo(q.w);
                }
                s0 += f0 - r0[j]; r0[j] = f0;
                s1 += f1 - r1[j]; r1[j] = f1;
                s2 += f2 - r2[j]; r2[j] = f2;
                s3 += f3 - r3[j]; r3[j] = f3;
                s4 += f4 - r4[j]; r4[j] = f4;
                rI[j] = f5; rJ[j] = f6;

                if (s >= 8) {
                    // center of output slice d_out = d_in-4, staged 4 steps ago
                    const float vi = rI[(j + 5) % 9];
                    const float vj = rJ[(j + 5) % 9];
                    const float Iu = vi * inv_k;
                    const float Ju = vj * inv_k;
                    const float cross = s4 - s0 * Ju - s1 * Iu + Iu * Ju * 729.0f;
                    const float Ivar  = s2 - 2.0f * s0 * Iu + Iu * Iu * 729.0f;
                    const float Jvar  = s3 - 2.0f * s1 * Ju + Ju * Ju * 729.0f;
                    local += (cross * cross) / (Ivar * Jvar + 1e-5f);
                }
            }
        }
    }

    __shared__ float sred[192];
    sred[t] = local;
    __syncthreads();
    if (t < 64) {
        float v = sred[t] + sred[t + 64] + sred[t + 128];
        #pragma unroll
        for (int off = 32; off; off >>= 1) v += __shfl_down(v, off);
        if (t == 0) {
            atomicAdd(out, v * (-1.0f / 14155776.0f));
        }
    }
}

extern "C" void kernel_launch(void* const* d_in, const int* in_sizes, int n_in,
                              void* d_out, int out_size, void* d_ws, size_t ws_size,
                              hipStream_t stream) {
    const float* I = (const float*)d_in[0];
    const float* J = (const float*)d_in[1];
    float* out = (float*)d_out;

    // Workspace: packed bf16x8 HW-summed volume, reused per batch: 113.2 MB.
    uint4* B = (uint4*)d_ws;

    zero_out_k<<<1, 1, 0, stream>>>(out);

    for (int b = 0; b < 2; ++b) {
        const float* Ib = I + (size_t)b * VOL;
        const float* Jb = J + (size_t)b * VOL;
        wh_pass<<<192 * 8, 192, 0, stream>>>(Ib, Jb, B);
        d_pass<<<192 * 8, 192, 0, stream>>>(B, out);
    }
}

// Round 5
// 256.851 us; speedup vs baseline: 2.1417x; 1.0702x over previous
//
#include <hip/hip_runtime.h>
#include <hip/hip_bf16.h>

#define WDIM 192
#define PLANE (192 * 192)
#define VOL (192 * 192 * 192)
#define HC 24          // h-rows produced per block in wh_pass
#define TR (HC + 8)    // tile rows incl. halo = 32
#define ROWW 200       // padded LDS row: 4 zero cols each side
#define DC 24          // d-slices per block in d_pass

__global__ void zero_out_k(float* out) { out[0] = 0.0f; }

// pack two floats -> one uint holding 2 bf16 (RN), lo = a, hi = b
static __device__ inline unsigned int pk_bf16(float a, float b) {
    union { __hip_bfloat162 v; unsigned int u; } cvt;
    cvt.v = __float22bfloat162_rn(make_float2(a, b));
    return cvt.u;
}
static __device__ inline float bf_lo(unsigned int u) {
    union { unsigned int u; float f; } c; c.u = u << 16; return c.f;
}
static __device__ inline float bf_hi(unsigned int u) {
    union { unsigned int u; float f; } c; c.u = u & 0xffff0000u; return c.f;
}

// --- Pass 1: fused W-box + H-box sums -> packed bf16x8 per voxel -----------
// LDS: one padded bf16-pair array (25.6 KB) -> 6 blocks/CU.
// Taps: single ds_read_b32 + unpack, no bounds checks (zero padding).
__global__ __launch_bounds__(192) void wh_pass(const float* __restrict__ I,
                                               const float* __restrict__ J,
                                               uint4* __restrict__ B) {
    __shared__ unsigned int sPK[TR * ROWW];   // 25600 B
    const int t = threadIdx.x;           // w
    const int d = blockIdx.x >> 3;
    const int c = blockIdx.x & 7;
    const int h0 = c * HC;

    const size_t dbase = (size_t)d * PLANE;

    // zero the 8 pad columns of each row (256 entries)
    for (int i = t; i < TR * 8; i += 192) {
        const int row = i >> 3;
        const int p = i & 7;
        const int col = (p < 4) ? p : (192 + p);
        sPK[row * ROWW + col] = 0u;
    }

    // cooperative staging: rows 0..31, cols 0..191 (+4 offset in LDS)
    #pragma unroll
    for (int i = 0; i < 8; ++i) {
        const int idx4 = i * 192 + t;        // 0..1535
        const int row  = idx4 / 48;          // 0..31
        const int col4 = (idx4 - row * 48) * 4;
        const int h = h0 - 4 + row;
        float4 vI = make_float4(0.f, 0.f, 0.f, 0.f);
        float4 vJ = vI;
        if (h >= 0 && h < WDIM) {
            vI = *(const float4*)(I + dbase + (size_t)h * WDIM + col4);
            vJ = *(const float4*)(J + dbase + (size_t)h * WDIM + col4);
        }
        uint4 u;
        u.x = pk_bf16(vI.x, vJ.x);
        u.y = pk_bf16(vI.y, vJ.y);
        u.z = pk_bf16(vI.z, vJ.z);
        u.w = pk_bf16(vI.w, vJ.w);
        *(uint4*)&sPK[row * ROWW + 4 + col4] = u;   // 16B-aligned
    }
    __syncthreads();

    float ring0[9], ring1[9], ring2[9], ring3[9], ring4[9];
    #pragma unroll
    for (int j = 0; j < 9; ++j) { ring0[j]=0.f; ring1[j]=0.f; ring2[j]=0.f; ring3[j]=0.f; ring4[j]=0.f; }
    float s0 = 0.f, s1 = 0.f, s2 = 0.f, s3 = 0.f, s4 = 0.f;

    #pragma unroll
    for (int o = 0; o < 4; ++o) {
        #pragma unroll
        for (int j = 0; j < 9; ++j) {
            const int s = o * 9 + j;
            if (s < TR) {
                const unsigned int* rowp = &sPK[s * ROWW + t]; // k=0..8 -> w=t-4+k
                float w0 = 0.f, w1 = 0.f, w2 = 0.f, w3 = 0.f, w4 = 0.f;
                #pragma unroll
                for (int k = 0; k < 9; ++k) {
                    const unsigned int u = rowp[k];
                    const float a = bf_lo(u);
                    const float b = bf_hi(u);
                    w0 += a; w1 += b;
                    w2 += a * a; w3 += b * b; w4 += a * b;
                }
                s0 += w0 - ring0[j]; ring0[j] = w0;
                s1 += w1 - ring1[j]; ring1[j] = w1;
                s2 += w2 - ring2[j]; ring2[j] = w2;
                s3 += w3 - ring3[j]; ring3[j] = w3;
                s4 += w4 - ring4[j]; ring4[j] = w4;

                if (s >= 8) {
                    const int h_out = h0 + s - 8;
                    const unsigned int cu = sPK[(s - 4) * ROWW + t + 4];
                    const float ci = bf_lo(cu);
                    const float cj = bf_hi(cu);
                    uint4 q;
                    q.x = pk_bf16(s0, s1);
                    q.y = pk_bf16(s2, s3);
                    q.z = pk_bf16(s4, ci);
                    q.w = pk_bf16(cj, 0.f);
                    B[dbase + (size_t)h_out * WDIM + t] = q;
                }
            }
        }
    }
}

// --- Pass 2: D-axis sliding box sum + NCC + reduction ----------------------
// Per o-group: batch-issue 9 guarded uint4 loads, then process.
__global__ __launch_bounds__(192) void d_pass(const uint4* __restrict__ B,
                                              float* __restrict__ out) {
    const int t = threadIdx.x;
    const int h = blockIdx.x >> 3;
    const int c = blockIdx.x & 7;
    const int d0 = c * DC;
    const int base_h = h * WDIM + t;

    float r0[9], r1[9], r2[9], r3[9], r4[9], rI[9], rJ[9];
    #pragma unroll
    for (int j = 0; j < 9; ++j) { r0[j]=0.f; r1[j]=0.f; r2[j]=0.f; r3[j]=0.f; r4[j]=0.f; rI[j]=0.f; rJ[j]=0.f; }
    float s0 = 0.f, s1 = 0.f, s2 = 0.f, s3 = 0.f, s4 = 0.f;

    const float inv_k = 1.0f / 729.0f;
    float local = 0.f;

    // steps s = 0..DC+7 : d_in = d0-4+s ; emit d_out = d_in-4 for s >= 8
    #pragma unroll
    for (int o = 0; o < 4; ++o) {
        uint4 q[9];
        #pragma unroll
        for (int j = 0; j < 9; ++j) {
            const int s = o * 9 + j;
            const int d_in = d0 - 4 + s;
            q[j] = make_uint4(0u, 0u, 0u, 0u);
            if (s < DC + 8 && d_in >= 0 && d_in < WDIM)
                q[j] = B[(size_t)d_in * PLANE + base_h];
        }
        #pragma unroll
        for (int j = 0; j < 9; ++j) {
            const int s = o * 9 + j;
            if (s < DC + 8) {
                const float f0 = bf_lo(q[j].x), f1 = bf_hi(q[j].x);
                const float f2 = bf_lo(q[j].y), f3 = bf_hi(q[j].y);
                const float f4 = bf_lo(q[j].z), f5 = bf_hi(q[j].z);
                const float f6 = bf_lo(q[j].w);
                s0 += f0 - r0[j]; r0[j] = f0;
                s1 += f1 - r1[j]; r1[j] = f1;
                s2 += f2 - r2[j]; r2[j] = f2;
                s3 += f3 - r3[j]; r3[j] = f3;
                s4 += f4 - r4[j]; r4[j] = f4;
                rI[j] = f5; rJ[j] = f6;

                if (s >= 8) {
                    const float vi = rI[(j + 5) % 9];   // staged 4 steps ago
                    const float vj = rJ[(j + 5) % 9];
                    const float Iu = vi * inv_k;
                    const float Ju = vj * inv_k;
                    const float cross = s4 - s0 * Ju - s1 * Iu + Iu * Ju * 729.0f;
                    const float Ivar  = s2 - 2.0f * s0 * Iu + Iu * Iu * 729.0f;
                    const float Jvar  = s3 - 2.0f * s1 * Ju + Ju * Ju * 729.0f;
                    local += (cross * cross) / (Ivar * Jvar + 1e-5f);
                }
            }
        }
    }

    __shared__ float sred[192];
    sred[t] = local;
    __syncthreads();
    if (t < 64) {
        float v = sred[t] + sred[t + 64] + sred[t + 128];
        #pragma unroll
        for (int off = 32; off; off >>= 1) v += __shfl_down(v, off);
        if (t == 0) {
            atomicAdd(out, v * (-1.0f / 14155776.0f));
        }
    }
}

extern "C" void kernel_launch(void* const* d_in, const int* in_sizes, int n_in,
                              void* d_out, int out_size, void* d_ws, size_t ws_size,
                              hipStream_t stream) {
    const float* I = (const float*)d_in[0];
    const float* J = (const float*)d_in[1];
    float* out = (float*)d_out;

    // Workspace: packed bf16x8 HW-summed volume, reused per batch: 113.2 MB.
    uint4* B = (uint4*)d_ws;

    zero_out_k<<<1, 1, 0, stream>>>(out);

    for (int b = 0; b < 2; ++b) {
        const float* Ib = I + (size_t)b * VOL;
        const float* Jb = J + (size_t)b * VOL;
        wh_pass<<<192 * 8, 192, 0, stream>>>(Ib, Jb, B);
        d_pass<<<192 * 8, 192, 0, stream>>>(B, out);
    }
}